// Round 15
// baseline (384.672 us; speedup 1.0000x reference)
//
#include <hip/hip_runtime.h>
#include <math.h>

// Problem constants (from reference setup_inputs)
#define NB   8192   // batch
#define NC   3755   // chars
#define NR   214    // radicals
#define NS   13     // structure classes
#define NSC  30     // stroke-count bins
#define NST  6      // stroke types
#define NH   64     // hidden
#define KTOP 20     // top_k
#define RPB  4      // rows per block in select kernel (one wave each)
#define NT   (RPB * 64)
#define NQT  15     // float4 slots per lane: ceil(938/64); 14 full + tail
#define NBIN 1024   // histogram bins (fallback only)
#define CAP  192    // candidate capacity per row (E[M]=85, sd 9 for N(0,1))

// monotonic float -> uint transform (ascending float => ascending unsigned key)
__device__ __forceinline__ unsigned sortkey(float x) {
    unsigned u = __float_as_uint(x);
    return (u & 0x80000000u) ? ~u : (u | 0x80000000u);
}
__device__ __forceinline__ float inv_sortkey(unsigned k) {
    unsigned u = (k & 0x80000000u) ? (k ^ 0x80000000u) : ~k;
    return __uint_as_float(u);
}
// count of set bits in m strictly below this lane
__device__ __forceinline__ int lane_prefix(unsigned long long m) {
    int c = __builtin_amdgcn_mbcnt_lo((unsigned)m, 0);
    return __builtin_amdgcn_mbcnt_hi((unsigned)(m >> 32), c);
}

// ============================ KERNEL P: prep ============================
// One wave per char: ballot radical_mask[c][*] != 0 into a 214-bit mask
// (8 u32 per char, top bits zero). 3.2 MB read, ~5 us.
__global__ __launch_bounds__(256) void prep_kernel(
    const int* __restrict__ radical_mask,
    unsigned*  __restrict__ ws_bits)      // (NC, 8) u32
{
    const int lane = threadIdx.x & 63;
    const int wave = threadIdx.x >> 6;
    const int c    = blockIdx.x * 4 + wave;
    if (c >= NC) return;                   // wave-uniform exit
    unsigned long long bits[4];
#pragma unroll
    for (int i = 0; i < 4; ++i) {
        int r = lane + i * 64;
        bool pred = (r < NR) && (radical_mask[(size_t)c * NR + r] != 0);
        bits[i] = __ballot(pred);
    }
    if (lane == 0) {
        uint4 wa = make_uint4((unsigned)bits[0], (unsigned)(bits[0] >> 32),
                              (unsigned)bits[1], (unsigned)(bits[1] >> 32));
        uint4 wb = make_uint4((unsigned)bits[2], (unsigned)(bits[2] >> 32),
                              (unsigned)bits[3], (unsigned)(bits[3] >> 32));
        reinterpret_cast<uint4*>(ws_bits)[(size_t)c * 2 + 0] = wa;
        reinterpret_cast<uint4*>(ws_bits)[(size_t)c * 2 + 1] = wb;
    }
}

// ============================ KERNEL A: select ============================
// Single-pass; ballot/prefix compaction (no LDS-atomic round-trip in the
// stream); 14 unconditional float4 iterations + tail; PLAIN stores (the R14
// non-temporal experiment cost +87MB HBM writes -- reverted).
__global__ __launch_bounds__(NT, 8) void select_kernel(
    const float* __restrict__ char_logits,
    float*       __restrict__ out,
    float*       __restrict__ ws_topv,   // (NB, KTOP)
    int*         __restrict__ ws_topi,   // (NB, KTOP)
    float*       __restrict__ ws_stat)   // (NB, 2): rowmax, sumexp
{
    const int tid  = threadIdx.x;
    const int lane = tid & 63;
    const int wave = tid >> 6;
    const int row  = blockIdx.x * RPB + wave;

    __shared__ unsigned           s_hist32[RPB / 2][NBIN]; // fallback only
    __shared__ unsigned long long s_cand[RPB][CAP];        // packed key|~idx
    __shared__ int s_cnt[RPB];                             // fallback only
    __shared__ int s_need[RPB];

    const int      hw  = wave >> 1;
    const unsigned hsh = (wave & 1) * 16;

    const size_t rowOff = (size_t)row * NC;
    const float* __restrict__ rin  = char_logits + rowOff;
    float*       __restrict__ rout = out + rowOff;

    const int a     = (int)((4 - (rowOff & 3)) & 3);
    const int nq    = (NC - a) >> 2;            // 938 always
    const int ntail = NC - a - 4 * nq;          // 3 - a

    int ext_idx = -1;
    if (lane < a)                           ext_idx = lane;
    else if (lane >= 8 && lane < 8 + ntail) ext_idx = a + 4 * nq + (lane - 8);

    const unsigned FLOORK = 0xC0000000u;        // sortkey(2.0f)
    float ext = -INFINITY;
    if (ext_idx >= 0) {
        ext = rin[ext_idx];
        rout[ext_idx] = ext;
    }
    float e0 = __expf(ext), e1 = 0.f, e2 = 0.f, e3 = 0.f;   // exp(-inf)=0
    float m0 = ext, m1 = -INFINITY, m2 = -INFINITY, m3 = -INFINITY;
    int base = 0;

    // ---- 14 unconditional iterations (q = lane + 64t < 938 for t<=13) ----
#pragma unroll
    for (int t = 0; t < 14; ++t) {
        const int q = lane + t * 64;
        float4 x = *reinterpret_cast<const float4*>(rin + a + 4 * q);
        *reinterpret_cast<float4*>(rout + a + 4 * q) = x;
        e0 += __expf(x.x); e1 += __expf(x.y);
        e2 += __expf(x.z); e3 += __expf(x.w);
        m0 = fmaxf(m0, x.x); m1 = fmaxf(m1, x.y);
        m2 = fmaxf(m2, x.z); m3 = fmaxf(m3, x.w);
        unsigned kk[4] = { sortkey(x.x), sortkey(x.y), sortkey(x.z), sortkey(x.w) };
#pragma unroll
        for (int j = 0; j < 4; ++j) {
            bool pred = kk[j] >= FLOORK;
            unsigned long long bal = __ballot(pred);
            if (pred) {
                int pos = base + lane_prefix(bal);
                if (pos < CAP)
                    s_cand[wave][pos] = ((unsigned long long)kk[j] << 32)
                                      | (0xFFFFFFFFu - (unsigned)(a + 4 * q + j));
            }
            base += (int)__popcll(bal);
        }
    }
    // ---- tail iteration (lanes with q = lane + 896 < 938) ----
    {
        const int q = lane + 896;
        const bool inb = q < nq;
        float4 x = make_float4(-INFINITY, -INFINITY, -INFINITY, -INFINITY);
        if (inb) {
            x = *reinterpret_cast<const float4*>(rin + a + 4 * q);
            *reinterpret_cast<float4*>(rout + a + 4 * q) = x;
        }
        e0 += __expf(x.x); e1 += __expf(x.y);
        e2 += __expf(x.z); e3 += __expf(x.w);
        m0 = fmaxf(m0, x.x); m1 = fmaxf(m1, x.y);
        m2 = fmaxf(m2, x.z); m3 = fmaxf(m3, x.w);
        unsigned kk[4] = { sortkey(x.x), sortkey(x.y), sortkey(x.z), sortkey(x.w) };
#pragma unroll
        for (int j = 0; j < 4; ++j) {
            bool pred = kk[j] >= FLOORK;          // -inf keys fail automatically
            unsigned long long bal = __ballot(pred);
            if (pred) {
                int pos = base + lane_prefix(bal);
                if (pos < CAP)
                    s_cand[wave][pos] = ((unsigned long long)kk[j] << 32)
                                      | (0xFFFFFFFFu - (unsigned)(a + 4 * q + j));
            }
            base += (int)__popcll(bal);
        }
    }
    // ---- ext element compaction (key of -inf fails the filter) ----
    {
        unsigned k = sortkey(ext);
        bool pred = k >= FLOORK;
        unsigned long long bal = __ballot(pred);
        if (pred) {
            int pos = base + lane_prefix(bal);
            if (pos < CAP)
                s_cand[wave][pos] = ((unsigned long long)k << 32)
                                  | (0xFFFFFFFFu - (unsigned)ext_idx);
        }
        base += (int)__popcll(bal);
    }

    float lmax = fmaxf(fmaxf(m0, m1), fmaxf(m2, m3));
#pragma unroll
    for (int off = 32; off > 0; off >>= 1) lmax = fmaxf(lmax, __shfl_xor(lmax, off));
    const float rowmax = lmax;
    float S = (e0 + e1) + (e2 + e3);
#pragma unroll
    for (int off = 32; off > 0; off >>= 1) S += __shfl_xor(S, off);

    int M = base;                                  // wave-uniform by construction
    const bool ok = (M >= KTOP) && (M <= CAP) && (fabsf(rowmax) <= 60.f);
    float sumexp = S * __expf(-rowmax);
    if (lane == 0) s_need[wave] = ok ? 0 : 1;
    __syncthreads();
    const int any = s_need[0] | s_need[1] | s_need[2] | s_need[3];

    if (any) {   // exact fallback (~never for N(0,1)); block-uniform barriers
        const bool bad = !ok;
        for (int i = tid; i < (RPB / 2) * NBIN; i += NT)
            (&s_hist32[0][0])[i] = 0u;
        __syncthreads();
        if (bad) {
            if (ext_idx >= 0) atomicAdd(&s_hist32[hw][sortkey(ext) >> 22], 1u << hsh);
            for (int t = 0; t < NQT; ++t) {
                int q = lane + t * 64;
                if (q < nq) {
                    float4 x = *reinterpret_cast<const float4*>(rin + a + 4 * q);
                    atomicAdd(&s_hist32[hw][sortkey(x.x) >> 22], 1u << hsh);
                    atomicAdd(&s_hist32[hw][sortkey(x.y) >> 22], 1u << hsh);
                    atomicAdd(&s_hist32[hw][sortkey(x.z) >> 22], 1u << hsh);
                    atomicAdd(&s_hist32[hw][sortkey(x.w) >> 22], 1u << hsh);
                }
            }
        }
        __syncthreads();
        int B0 = 0;
        if (bad) {
            int bb = (int)(sortkey(rowmax) >> 22), cum = 0;
            while (bb >= 0) {
                cum += (int)((s_hist32[hw][bb] >> hsh) & 0xFFFFu);
                if (cum >= KTOP) break;
                --bb;
            }
            B0 = (bb < 0) ? 0 : bb;
            if (lane == 0) s_cnt[wave] = 0;
        }
        __syncthreads();
        if (bad) {
            float f0 = 0.f, f1 = 0.f, f2 = 0.f, f3 = 0.f;
            if (ext_idx >= 0) {
                f0 += __expf(ext - rowmax);
                unsigned k = sortkey(ext);
                if ((int)(k >> 22) >= B0) {
                    int pos = atomicAdd(&s_cnt[wave], 1);
                    if (pos < CAP)
                        s_cand[wave][pos] = ((unsigned long long)k << 32) | (0xFFFFFFFFu - (unsigned)ext_idx);
                }
            }
            for (int t = 0; t < NQT; ++t) {
                int q = lane + t * 64;
                if (q < nq) {
                    float4 x = *reinterpret_cast<const float4*>(rin + a + 4 * q);
                    f0 += __expf(x.x - rowmax); f1 += __expf(x.y - rowmax);
                    f2 += __expf(x.z - rowmax); f3 += __expf(x.w - rowmax);
                    unsigned kk[4] = { sortkey(x.x), sortkey(x.y), sortkey(x.z), sortkey(x.w) };
#pragma unroll
                    for (int j = 0; j < 4; ++j) {
                        if ((int)(kk[j] >> 22) >= B0) {
                            int pos = atomicAdd(&s_cnt[wave], 1);
                            if (pos < CAP)
                                s_cand[wave][pos] = ((unsigned long long)kk[j] << 32)
                                                  | (0xFFFFFFFFu - (unsigned)(a + 4 * q + j));
                        }
                    }
                }
            }
            float ls = (f0 + f1) + (f2 + f3);
#pragma unroll
            for (int off = 32; off > 0; off >>= 1) ls += __shfl_xor(ls, off);
            sumexp = ls;
            M = s_cnt[wave]; if (M > CAP) M = CAP;
        }
    }

    // ---- rank selection: packed compare (val desc, idx asc) -> workspace ----
    for (int c = lane; c < M; c += 64) {
        unsigned long long pc = s_cand[wave][c];
        int rank = 0;
        for (int j = 0; j < M; ++j) rank += (s_cand[wave][j] > pc) ? 1 : 0;
        if (rank < KTOP) {
            ws_topv[(size_t)row * KTOP + rank] = inv_sortkey((unsigned)(pc >> 32));
            ws_topi[(size_t)row * KTOP + rank] = (int)(0xFFFFFFFFu - (unsigned)(pc & 0xFFFFFFFFu));
        }
    }
    if (lane == 0) {
        ws_stat[2 * row + 0] = rowmax;
        ws_stat[2 * row + 1] = sumexp;
    }
}

// ============================ KERNEL B: rerank ============================
// block-per-row; det/cnt via per-char bitmask (2 uniform uint4 loads +
// register bit-select) -- no vector global loads per candidate.
__global__ __launch_bounds__(256, 8) void rerank_kernel(
    const float* __restrict__ radical_logits,
    const float* __restrict__ structure,
    const float* __restrict__ stroke_count,
    const float* __restrict__ stroke_types,
    const int*   __restrict__ structure_label,
    const int*   __restrict__ stroke_count_label,
    const float* __restrict__ stroke_type_sig,
    const float* __restrict__ W1,
    const float* __restrict__ b1,
    const float* __restrict__ W2,
    const float* __restrict__ b2,
    const float* __restrict__ rw,
    const float* __restrict__ ws_topv,
    const int*   __restrict__ ws_topi,
    const float* __restrict__ ws_stat,
    const unsigned* __restrict__ ws_bits,
    float*       __restrict__ out)
{
    const int row  = blockIdx.x;
    const int tid  = threadIdx.x;
    const int lane = tid & 63;
    const int wave = tid >> 6;

    __shared__ float s_probs[256];   // zero-padded beyond NR
    __shared__ float s_struct[NS];
    __shared__ float s_aux[8];       // [0..5] normalized stroke_types, [6] stroke_pred
    __shared__ float s_topv[KTOP];
    __shared__ int   s_topi[KTOP];
    __shared__ float s_stat2[2];

    s_probs[tid] = (tid < NR)
        ? 1.f / (1.f + __expf(-radical_logits[(size_t)row * NR + tid])) : 0.f;
    if (tid < KTOP) {
        s_topv[tid] = ws_topv[(size_t)row * KTOP + tid];
        s_topi[tid] = ws_topi[(size_t)row * KTOP + tid];
    }
    if (tid == 216) {
        float sv[NS]; float m = -INFINITY;
#pragma unroll
        for (int i = 0; i < NS; ++i) { sv[i] = structure[(size_t)row * NS + i]; m = fmaxf(m, sv[i]); }
        float s = 0.f;
#pragma unroll
        for (int i = 0; i < NS; ++i) { sv[i] = __expf(sv[i] - m); s += sv[i]; }
        float inv = 1.f / s;
#pragma unroll
        for (int i = 0; i < NS; ++i) s_struct[i] = sv[i] * inv;
    } else if (tid == 217) {
        float bv = -INFINITY; int bi = 0;
#pragma unroll
        for (int i = 0; i < NSC; ++i) {
            float x = stroke_count[(size_t)row * NSC + i];
            if (x > bv) { bv = x; bi = i; }
        }
        s_aux[6] = (float)bi;
    } else if (tid == 218) {
        float t6[NST]; float ss = 0.f;
#pragma unroll
        for (int i = 0; i < NST; ++i) { t6[i] = stroke_types[(size_t)row * NST + i]; ss += t6[i] * t6[i]; }
        float inv = 1.f / fmaxf(sqrtf(ss), 1e-12f);
#pragma unroll
        for (int i = 0; i < NST; ++i) s_aux[i] = t6[i] * inv;
    } else if (tid == 219) {
        s_stat2[0] = ws_stat[2 * row + 0];
        s_stat2[1] = ws_stat[2 * row + 1];
    }
    __syncthreads();

    // preload this lane's 4 prob slots (zero-padded)
    const float p0 = s_probs[lane];
    const float p1 = s_probs[lane + 64];
    const float p2 = s_probs[lane + 128];
    const float p3 = s_probs[lane + 192];
    float psum = p0 + p1 + p2 + p3;
#pragma unroll
    for (int off = 32; off > 0; off >>= 1) psum += __shfl_xor(psum, off);
    const float total = psum;

    const float rowmax = s_stat2[0];
    const float sumexp = s_stat2[1];
    const float b1v = b1[lane];
    float w1v[6];
#pragma unroll
    for (int j = 0; j < 6; ++j) w1v[j] = W1[j * NH + lane];
    const float w2v = W2[lane];
    const float b2v = b2[0];
    const float wrk = rw[0];
    const float spred = s_aux[6];
    const unsigned l5 = lane & 31;
    const bool hi = lane >= 32;

    // ---- 5 candidates per wave ----
#pragma unroll
    for (int j = 0; j < KTOP / 4; ++j) {
        const int   k  = wave * (KTOP / 4) + j;
        const int   ci = __builtin_amdgcn_readfirstlane(s_topi[k]);
        const float tv = s_topv[k];

        const uint4* bq = reinterpret_cast<const uint4*>(ws_bits) + (size_t)ci * 2;
        const uint4 wa = bq[0], wb = bq[1];
        // cnt = popcount of the 214-bit mask (exact integer, == float sum of 0/1)
        float cnt = (float)(__popc(wa.x) + __popc(wa.y) + __popc(wa.z) + __popc(wa.w)
                          + __popc(wb.x) + __popc(wb.y) + __popc(wb.z));
        // det: same per-lane accumulation order as the original load-based loop
        float det = 0.f;
        det += ((( hi ? wa.y : wa.x) >> l5) & 1u) ? p0 : 0.f;
        det += ((( hi ? wa.w : wa.z) >> l5) & 1u) ? p1 : 0.f;
        det += ((( hi ? wb.y : wb.x) >> l5) & 1u) ? p2 : 0.f;
        det += ((( hi ? wb.w : wb.z) >> l5) & 1u) ? p3 : 0.f;
#pragma unroll
        for (int off = 32; off > 0; off >>= 1) det += __shfl_xor(det, off);

        float f1 = det / fmaxf(cnt, 1.f);
        float f2 = (total - det) / fmaxf(total, 1e-6f);
        float f3 = s_struct[structure_label[ci]];
        float f4 = fabsf(spred - (float)stroke_count_label[ci]) * (1.f / 29.f);
        float sig[NST]; float ss = 0.f;
#pragma unroll
        for (int i = 0; i < NST; ++i) { sig[i] = stroke_type_sig[(size_t)ci * NST + i]; ss += sig[i] * sig[i]; }
        float nrm = sqrtf(ss);
        float has = (nrm > 1e-6f) ? 1.f : 0.f;
        float add = 1e-8f * (1.f - has);
        float ss2 = 0.f;
#pragma unroll
        for (int i = 0; i < NST; ++i) { sig[i] += add; ss2 += sig[i] * sig[i]; }
        float inv = 1.f / fmaxf(sqrtf(ss2), 1e-12f);
        float dot = 0.f;
#pragma unroll
        for (int i = 0; i < NST; ++i) dot += s_aux[i] * sig[i] * inv;
        float f5 = dot * has;
        float f6 = __expf(tv - rowmax) / sumexp;

        float acc = b1v + f1 * w1v[0] + f2 * w1v[1] + f3 * w1v[2]
                        + f4 * w1v[3] + f5 * w1v[4] + f6 * w1v[5];
        float h = fmaxf(acc, 0.f);
        float part = h * w2v;
#pragma unroll
        for (int off = 32; off > 0; off >>= 1) part += __shfl_xor(part, off);
        if (lane == 0) out[(size_t)row * NC + ci] = tv + wrk * (part + b2v);
    }
}

extern "C" void kernel_launch(void* const* d_in, const int* in_sizes, int n_in,
                              void* d_out, int out_size, void* d_ws, size_t ws_size,
                              hipStream_t stream) {
    (void)in_sizes; (void)n_in; (void)out_size; (void)ws_size;
    const float* char_logits        = (const float*)d_in[0];
    const float* radical_logits     = (const float*)d_in[1];
    const float* structure          = (const float*)d_in[2];
    const float* stroke_count       = (const float*)d_in[3];
    const float* stroke_types       = (const float*)d_in[4];
    const int*   radical_mask       = (const int*)d_in[5];
    const int*   structure_label    = (const int*)d_in[6];
    const int*   stroke_count_label = (const int*)d_in[7];
    const float* stroke_type_sig    = (const float*)d_in[8];
    const float* W1                 = (const float*)d_in[9];
    const float* b1                 = (const float*)d_in[10];
    const float* W2                 = (const float*)d_in[11];
    const float* b2                 = (const float*)d_in[12];
    const float* rw                 = (const float*)d_in[13];
    float* out = (float*)d_out;

    // workspace: topv (NB*KTOP f32) | topi (NB*KTOP i32) | stat (NB*2 f32)
    //          | bits (NC*8 u32)  -- total ~1.50 MB, 16B-aligned sections
    float*    ws_topv = (float*)d_ws;
    int*      ws_topi = (int*)(ws_topv + (size_t)NB * KTOP);
    float*    ws_stat = (float*)(ws_topi + (size_t)NB * KTOP);
    unsigned* ws_bits = (unsigned*)(ws_stat + (size_t)NB * 2);

    prep_kernel<<<(NC + 3) / 4, 256, 0, stream>>>(radical_mask, ws_bits);
    select_kernel<<<NB / RPB, NT, 0, stream>>>(char_logits, out, ws_topv, ws_topi, ws_stat);
    rerank_kernel<<<NB, 256, 0, stream>>>(
        radical_logits, structure, stroke_count, stroke_types,
        structure_label, stroke_count_label, stroke_type_sig,
        W1, b1, W2, b2, rw, ws_topv, ws_topi, ws_stat, ws_bits, out);
}

// Round 16
// 338.864 us; speedup vs baseline: 1.1352x; 1.1352x over previous
//
#include <hip/hip_runtime.h>
#include <math.h>

// Problem constants (from reference setup_inputs)
#define NB   8192   // batch
#define NC   3755   // chars
#define NR   214    // radicals
#define NS   13     // structure classes
#define NSC  30     // stroke-count bins
#define NST  6      // stroke types
#define NH   64     // hidden
#define KTOP 20     // top_k
#define RPB  4      // rows per block (one wave each)
#define NT   (RPB * 64)
#define NQT  15     // float4 slots per lane: ceil(938/64)
#define NBIN 1024   // histogram bins (fallback only)
#define CAP  192    // candidate capacity per row (E[M]=85, sd 9 for N(0,1))

// monotonic float -> uint transform (ascending float => ascending unsigned key)
__device__ __forceinline__ unsigned sortkey(float x) {
    unsigned u = __float_as_uint(x);
    return (u & 0x80000000u) ? ~u : (u | 0x80000000u);
}
__device__ __forceinline__ float inv_sortkey(unsigned k) {
    unsigned u = (k & 0x80000000u) ? (k ^ 0x80000000u) : ~k;
    return __uint_as_float(u);
}

// ============================ KERNEL P: prep ============================
// One wave per char: ballot radical_mask[c][*] != 0 into a 214-bit mask
// (8 u32 per char, top bits zero). 3.2 MB read, ~5 us.
__global__ __launch_bounds__(256) void prep_kernel(
    const int* __restrict__ radical_mask,
    unsigned*  __restrict__ ws_bits)      // (NC, 8) u32
{
    const int lane = threadIdx.x & 63;
    const int wave = threadIdx.x >> 6;
    const int c    = blockIdx.x * 4 + wave;
    if (c >= NC) return;                   // wave-uniform exit
    unsigned long long bits[4];
#pragma unroll
    for (int i = 0; i < 4; ++i) {
        int r = lane + i * 64;
        bool pred = (r < NR) && (radical_mask[(size_t)c * NR + r] != 0);
        bits[i] = __ballot(pred);
    }
    if (lane == 0) {
        uint4 wa = make_uint4((unsigned)bits[0], (unsigned)(bits[0] >> 32),
                              (unsigned)bits[1], (unsigned)(bits[1] >> 32));
        uint4 wb = make_uint4((unsigned)bits[2], (unsigned)(bits[2] >> 32),
                              (unsigned)bits[3], (unsigned)(bits[3] >> 32));
        reinterpret_cast<uint4*>(ws_bits)[(size_t)c * 2 + 0] = wa;
        reinterpret_cast<uint4*>(ws_bits)[(size_t)c * 2 + 1] = wb;
    }
}

// ============================ KERNEL A: select ============================
// R13-exact loop structure (conditional iteration, LDS-atomic compaction,
// adjacent load/store -- the measured-good 89.5us/125MB-write version; the
// R14 ballot/unconditional restructure bloated HBM traffic +130MB and is
// reverted) + ONE new element: 1-deep float4 prefetch (2 loads in flight).
__global__ __launch_bounds__(NT, 8) void select_kernel(
    const float* __restrict__ char_logits,
    float*       __restrict__ out,
    float*       __restrict__ ws_topv,   // (NB, KTOP)
    int*         __restrict__ ws_topi,   // (NB, KTOP)
    float*       __restrict__ ws_stat)   // (NB, 2): rowmax, sumexp
{
    const int tid  = threadIdx.x;
    const int lane = tid & 63;
    const int wave = tid >> 6;
    const int row  = blockIdx.x * RPB + wave;

    __shared__ unsigned           s_hist32[RPB / 2][NBIN]; // fallback only
    __shared__ unsigned long long s_cand[RPB][CAP];        // packed key|~idx
    __shared__ int s_cnt[RPB];
    __shared__ int s_need[RPB];

    const int      hw  = wave >> 1;
    const unsigned hsh = (wave & 1) * 16;

    const size_t rowOff = (size_t)row * NC;
    const float* __restrict__ rin  = char_logits + rowOff;
    float*       __restrict__ rout = out + rowOff;

    const int a     = (int)((4 - (rowOff & 3)) & 3);
    const int nq    = (NC - a) >> 2;            // 938 always
    const int ntail = NC - a - 4 * nq;          // 3 - a

    int ext_idx = -1;
    if (lane < a)                           ext_idx = lane;
    else if (lane >= 8 && lane < 8 + ntail) ext_idx = a + 4 * nq + (lane - 8);

    if (tid < RPB) s_cnt[tid] = 0;
    __syncthreads();                                   // B1 (cnt zero visible)

    // ---- single fused pass with 1-deep prefetch ----
    const unsigned FLOORK = 0xC0000000u;               // sortkey(2.0f)
    float ext = -INFINITY;
    if (ext_idx >= 0) {
        ext = rin[ext_idx];
        rout[ext_idx] = ext;
    }
    float e0 = __expf(ext), e1 = 0.f, e2 = 0.f, e3 = 0.f;   // exp(-inf)=0
    float m0 = ext, m1 = -INFINITY, m2 = -INFINITY, m3 = -INFINITY;

    float4 nxt = make_float4(-INFINITY, -INFINITY, -INFINITY, -INFINITY);
    if (lane < nq) nxt = *reinterpret_cast<const float4*>(rin + a + 4 * lane);

    for (int t = 0; t < NQT; ++t) {
        const int q = lane + t * 64;
        const float4 x = nxt;
        // prefetch next iteration's data before processing current
        nxt = make_float4(-INFINITY, -INFINITY, -INFINITY, -INFINITY);
        if (t + 1 < NQT) {
            int qn = lane + (t + 1) * 64;
            if (qn < nq) nxt = *reinterpret_cast<const float4*>(rin + a + 4 * qn);
        }
        if (q < nq) {
            *reinterpret_cast<float4*>(rout + a + 4 * q) = x;
            e0 += __expf(x.x); e1 += __expf(x.y);
            e2 += __expf(x.z); e3 += __expf(x.w);
            m0 = fmaxf(m0, x.x); m1 = fmaxf(m1, x.y);
            m2 = fmaxf(m2, x.z); m3 = fmaxf(m3, x.w);
            unsigned kk[4] = { sortkey(x.x), sortkey(x.y), sortkey(x.z), sortkey(x.w) };
#pragma unroll
            for (int j = 0; j < 4; ++j) {
                if (kk[j] >= FLOORK) {
                    int pos = atomicAdd(&s_cnt[wave], 1);
                    if (pos < CAP)
                        s_cand[wave][pos] = ((unsigned long long)kk[j] << 32)
                                          | (0xFFFFFFFFu - (unsigned)(a + 4 * q + j));
                }
            }
        }
    }
    // ---- ext element compaction ----
    if (ext_idx >= 0) {
        unsigned k = sortkey(ext);
        if (k >= FLOORK) {
            int pos = atomicAdd(&s_cnt[wave], 1);
            if (pos < CAP)
                s_cand[wave][pos] = ((unsigned long long)k << 32)
                                  | (0xFFFFFFFFu - (unsigned)ext_idx);
        }
    }

    float lmax = fmaxf(fmaxf(m0, m1), fmaxf(m2, m3));
#pragma unroll
    for (int off = 32; off > 0; off >>= 1) lmax = fmaxf(lmax, __shfl_xor(lmax, off));
    const float rowmax = lmax;
    float S = (e0 + e1) + (e2 + e3);
#pragma unroll
    for (int off = 32; off > 0; off >>= 1) S += __shfl_xor(S, off);

    int M = s_cnt[wave];     // own-wave LDS ops ordered; value final for this wave
    const bool ok = (M >= KTOP) && (M <= CAP) && (fabsf(rowmax) <= 60.f);
    float sumexp = S * __expf(-rowmax);
    if (lane == 0) s_need[wave] = ok ? 0 : 1;
    __syncthreads();                                   // B2
    const int any = s_need[0] | s_need[1] | s_need[2] | s_need[3];

    if (any) {   // exact fallback (~never for N(0,1)); block-uniform barriers
        const bool bad = !ok;
        for (int i = tid; i < (RPB / 2) * NBIN; i += NT)
            (&s_hist32[0][0])[i] = 0u;
        __syncthreads();
        if (bad) {
            if (ext_idx >= 0) atomicAdd(&s_hist32[hw][sortkey(ext) >> 22], 1u << hsh);
            for (int t = 0; t < NQT; ++t) {
                int q = lane + t * 64;
                if (q < nq) {
                    float4 x = *reinterpret_cast<const float4*>(rin + a + 4 * q);
                    atomicAdd(&s_hist32[hw][sortkey(x.x) >> 22], 1u << hsh);
                    atomicAdd(&s_hist32[hw][sortkey(x.y) >> 22], 1u << hsh);
                    atomicAdd(&s_hist32[hw][sortkey(x.z) >> 22], 1u << hsh);
                    atomicAdd(&s_hist32[hw][sortkey(x.w) >> 22], 1u << hsh);
                }
            }
        }
        __syncthreads();
        int B0 = 0;
        if (bad) {
            int bb = (int)(sortkey(rowmax) >> 22), cum = 0;
            while (bb >= 0) {
                cum += (int)((s_hist32[hw][bb] >> hsh) & 0xFFFFu);
                if (cum >= KTOP) break;
                --bb;
            }
            B0 = (bb < 0) ? 0 : bb;
            if (lane == 0) s_cnt[wave] = 0;
        }
        __syncthreads();
        if (bad) {
            float f0 = 0.f, f1 = 0.f, f2 = 0.f, f3 = 0.f;
            if (ext_idx >= 0) {
                f0 += __expf(ext - rowmax);
                unsigned k = sortkey(ext);
                if ((int)(k >> 22) >= B0) {
                    int pos = atomicAdd(&s_cnt[wave], 1);
                    if (pos < CAP)
                        s_cand[wave][pos] = ((unsigned long long)k << 32) | (0xFFFFFFFFu - (unsigned)ext_idx);
                }
            }
            for (int t = 0; t < NQT; ++t) {
                int q = lane + t * 64;
                if (q < nq) {
                    float4 x = *reinterpret_cast<const float4*>(rin + a + 4 * q);
                    f0 += __expf(x.x - rowmax); f1 += __expf(x.y - rowmax);
                    f2 += __expf(x.z - rowmax); f3 += __expf(x.w - rowmax);
                    unsigned kk[4] = { sortkey(x.x), sortkey(x.y), sortkey(x.z), sortkey(x.w) };
#pragma unroll
                    for (int j = 0; j < 4; ++j) {
                        if ((int)(kk[j] >> 22) >= B0) {
                            int pos = atomicAdd(&s_cnt[wave], 1);
                            if (pos < CAP)
                                s_cand[wave][pos] = ((unsigned long long)kk[j] << 32)
                                                  | (0xFFFFFFFFu - (unsigned)(a + 4 * q + j));
                        }
                    }
                }
            }
            float ls = (f0 + f1) + (f2 + f3);
#pragma unroll
            for (int off = 32; off > 0; off >>= 1) ls += __shfl_xor(ls, off);
            sumexp = ls;
            M = s_cnt[wave]; if (M > CAP) M = CAP;
        }
    }

    // ---- rank selection: packed compare (val desc, idx asc) -> workspace ----
    for (int c = lane; c < M; c += 64) {
        unsigned long long pc = s_cand[wave][c];
        int rank = 0;
        for (int j = 0; j < M; ++j) rank += (s_cand[wave][j] > pc) ? 1 : 0;
        if (rank < KTOP) {
            ws_topv[(size_t)row * KTOP + rank] = inv_sortkey((unsigned)(pc >> 32));
            ws_topi[(size_t)row * KTOP + rank] = (int)(0xFFFFFFFFu - (unsigned)(pc & 0xFFFFFFFFu));
        }
    }
    if (lane == 0) {
        ws_stat[2 * row + 0] = rowmax;
        ws_stat[2 * row + 1] = sumexp;
    }
}

// ============================ KERNEL B: rerank ============================
// WAVE-per-row (2048 blocks x 4 waves; 8192 waves = full device residency).
// Each wave: prologue + all 20 candidates. One cheap symmetric barrier.
// det/cnt via per-char bitmask (2 uniform uint4 loads + register bit-select).
__global__ __launch_bounds__(256, 8) void rerank_kernel(
    const float* __restrict__ radical_logits,
    const float* __restrict__ structure,
    const float* __restrict__ stroke_count,
    const float* __restrict__ stroke_types,
    const int*   __restrict__ structure_label,
    const int*   __restrict__ stroke_count_label,
    const float* __restrict__ stroke_type_sig,
    const float* __restrict__ W1,
    const float* __restrict__ b1,
    const float* __restrict__ W2,
    const float* __restrict__ b2,
    const float* __restrict__ rw,
    const float* __restrict__ ws_topv,
    const int*   __restrict__ ws_topi,
    const float* __restrict__ ws_stat,
    const unsigned* __restrict__ ws_bits,
    float*       __restrict__ out)
{
    const int tid  = threadIdx.x;
    const int lane = tid & 63;
    const int wave = tid >> 6;
    const int row  = blockIdx.x * 4 + wave;   // grid 2048, NB = 2048*4

    __shared__ float s_probs[4][256];   // zero-padded beyond NR
    __shared__ float s_struct[4][NS];
    __shared__ float s_aux[4][8];       // [0..5] normalized stroke_types, [6] stroke_pred
    __shared__ float s_topv[4][KTOP];
    __shared__ int   s_topi[4][KTOP];
    __shared__ float s_stat2[4][2];

    // ---- prologue: each wave fills its own row's state (symmetric) ----
#pragma unroll
    for (int i = 0; i < 4; ++i) {
        int r = lane + i * 64;
        s_probs[wave][r] = (r < NR)
            ? 1.f / (1.f + __expf(-radical_logits[(size_t)row * NR + r])) : 0.f;
    }
    if (lane < KTOP) {
        s_topv[wave][lane] = ws_topv[(size_t)row * KTOP + lane];
        s_topi[wave][lane] = ws_topi[(size_t)row * KTOP + lane];
    } else if (lane == 24) {
        s_stat2[wave][0] = ws_stat[2 * row + 0];
        s_stat2[wave][1] = ws_stat[2 * row + 1];
    } else if (lane == 25) {
        float sv[NS]; float m = -INFINITY;
#pragma unroll
        for (int i = 0; i < NS; ++i) { sv[i] = structure[(size_t)row * NS + i]; m = fmaxf(m, sv[i]); }
        float s = 0.f;
#pragma unroll
        for (int i = 0; i < NS; ++i) { sv[i] = __expf(sv[i] - m); s += sv[i]; }
        float inv = 1.f / s;
#pragma unroll
        for (int i = 0; i < NS; ++i) s_struct[wave][i] = sv[i] * inv;
    } else if (lane == 26) {
        float bv = -INFINITY; int bi = 0;
#pragma unroll
        for (int i = 0; i < NSC; ++i) {
            float x = stroke_count[(size_t)row * NSC + i];
            if (x > bv) { bv = x; bi = i; }
        }
        s_aux[wave][6] = (float)bi;
    } else if (lane == 27) {
        float t6[NST]; float ss = 0.f;
#pragma unroll
        for (int i = 0; i < NST; ++i) { t6[i] = stroke_types[(size_t)row * NST + i]; ss += t6[i] * t6[i]; }
        float inv = 1.f / fmaxf(sqrtf(ss), 1e-12f);
#pragma unroll
        for (int i = 0; i < NST; ++i) s_aux[wave][i] = t6[i] * inv;
    }
    __syncthreads();   // symmetric across waves -> cheap

    // preload this lane's 4 prob slots (zero-padded)
    const float p0 = s_probs[wave][lane];
    const float p1 = s_probs[wave][lane + 64];
    const float p2 = s_probs[wave][lane + 128];
    const float p3 = s_probs[wave][lane + 192];
    float psum = p0 + p1 + p2 + p3;
#pragma unroll
    for (int off = 32; off > 0; off >>= 1) psum += __shfl_xor(psum, off);
    const float total = psum;

    const float rowmax = s_stat2[wave][0];
    const float sumexp = s_stat2[wave][1];
    const float b1v = b1[lane];
    float w1v[6];
#pragma unroll
    for (int j = 0; j < 6; ++j) w1v[j] = W1[j * NH + lane];
    const float w2v = W2[lane];
    const float b2v = b2[0];
    const float wrk = rw[0];
    const float spred = s_aux[wave][6];
    const unsigned l5 = lane & 31;
    const bool hi = lane >= 32;

    // ---- all 20 candidates of this wave's row ----
    for (int k = 0; k < KTOP; ++k) {
        const int   ci = __builtin_amdgcn_readfirstlane(s_topi[wave][k]);
        const float tv = s_topv[wave][k];

        const uint4* bq = reinterpret_cast<const uint4*>(ws_bits) + (size_t)ci * 2;
        const uint4 wa = bq[0], wb = bq[1];
        // cnt = popcount of the 214-bit mask (exact integer == float sum of 0/1)
        float cnt = (float)(__popc(wa.x) + __popc(wa.y) + __popc(wa.z) + __popc(wa.w)
                          + __popc(wb.x) + __popc(wb.y) + __popc(wb.z));
        // det: same per-lane accumulation order as the original load-based loop
        float det = 0.f;
        det += ((( hi ? wa.y : wa.x) >> l5) & 1u) ? p0 : 0.f;
        det += ((( hi ? wa.w : wa.z) >> l5) & 1u) ? p1 : 0.f;
        det += ((( hi ? wb.y : wb.x) >> l5) & 1u) ? p2 : 0.f;
        det += ((( hi ? wb.w : wb.z) >> l5) & 1u) ? p3 : 0.f;
#pragma unroll
        for (int off = 32; off > 0; off >>= 1) det += __shfl_xor(det, off);

        float f1 = det / fmaxf(cnt, 1.f);
        float f2 = (total - det) / fmaxf(total, 1e-6f);
        float f3 = s_struct[wave][structure_label[ci]];
        float f4 = fabsf(spred - (float)stroke_count_label[ci]) * (1.f / 29.f);
        float sig[NST]; float ss = 0.f;
#pragma unroll
        for (int i = 0; i < NST; ++i) { sig[i] = stroke_type_sig[(size_t)ci * NST + i]; ss += sig[i] * sig[i]; }
        float nrm = sqrtf(ss);
        float has = (nrm > 1e-6f) ? 1.f : 0.f;
        float add = 1e-8f * (1.f - has);
        float ss2 = 0.f;
#pragma unroll
        for (int i = 0; i < NST; ++i) { sig[i] += add; ss2 += sig[i] * sig[i]; }
        float inv = 1.f / fmaxf(sqrtf(ss2), 1e-12f);
        float dot = 0.f;
#pragma unroll
        for (int i = 0; i < NST; ++i) dot += s_aux[wave][i] * sig[i] * inv;
        float f5 = dot * has;
        float f6 = __expf(tv - rowmax) / sumexp;

        float acc = b1v + f1 * w1v[0] + f2 * w1v[1] + f3 * w1v[2]
                        + f4 * w1v[3] + f5 * w1v[4] + f6 * w1v[5];
        float h = fmaxf(acc, 0.f);
        float part = h * w2v;
#pragma unroll
        for (int off = 32; off > 0; off >>= 1) part += __shfl_xor(part, off);
        if (lane == 0) out[(size_t)row * NC + ci] = tv + wrk * (part + b2v);
    }
}

extern "C" void kernel_launch(void* const* d_in, const int* in_sizes, int n_in,
                              void* d_out, int out_size, void* d_ws, size_t ws_size,
                              hipStream_t stream) {
    (void)in_sizes; (void)n_in; (void)out_size; (void)ws_size;
    const float* char_logits        = (const float*)d_in[0];
    const float* radical_logits     = (const float*)d_in[1];
    const float* structure          = (const float*)d_in[2];
    const float* stroke_count       = (const float*)d_in[3];
    const float* stroke_types       = (const float*)d_in[4];
    const int*   radical_mask       = (const int*)d_in[5];
    const int*   structure_label    = (const int*)d_in[6];
    const int*   stroke_count_label = (const int*)d_in[7];
    const float* stroke_type_sig    = (const float*)d_in[8];
    const float* W1                 = (const float*)d_in[9];
    const float* b1                 = (const float*)d_in[10];
    const float* W2                 = (const float*)d_in[11];
    const float* b2                 = (const float*)d_in[12];
    const float* rw                 = (const float*)d_in[13];
    float* out = (float*)d_out;

    // workspace: topv (NB*KTOP f32) | topi (NB*KTOP i32) | stat (NB*2 f32)
    //          | bits (NC*8 u32)  -- total ~1.50 MB, 16B-aligned sections
    float*    ws_topv = (float*)d_ws;
    int*      ws_topi = (int*)(ws_topv + (size_t)NB * KTOP);
    float*    ws_stat = (float*)(ws_topi + (size_t)NB * KTOP);
    unsigned* ws_bits = (unsigned*)(ws_stat + (size_t)NB * 2);

    prep_kernel<<<(NC + 3) / 4, 256, 0, stream>>>(radical_mask, ws_bits);
    select_kernel<<<NB / RPB, NT, 0, stream>>>(char_logits, out, ws_topv, ws_topi, ws_stat);
    rerank_kernel<<<NB / 4, 256, 0, stream>>>(
        radical_logits, structure, stroke_count, stroke_types,
        structure_label, stroke_count_label, stroke_type_sig,
        W1, b1, W2, b2, rw, ws_topv, ws_topi, ws_stat, ws_bits, out);
}